// Round 1
// baseline (599.066 us; speedup 1.0000x reference)
//
#include <hip/hip_runtime.h>

// ---------------------------------------------------------------------------
// KAN 2-layer forward on MI355X.
//   layer = silu(x)@Wb^T + b_splines(x) contracted with (Ws*scaler)
// Folded into one bf16 MFMA GEMM per layer with K = features*8:
//   kk = i*8 + t : t=0 -> silu(x_i), t=1..6 -> cubic B-spline bases, t=7 -> 0 pad
// Weights pre-packed to bf16 [n][kk] by prep_w. LayerNorm separate kernel.
// ---------------------------------------------------------------------------

typedef short  s16x8 __attribute__((ext_vector_type(8)));   // 8 bf16 (4 VGPRs)
typedef float  f32x4 __attribute__((ext_vector_type(4)));

__device__ __forceinline__ unsigned short f2bf(float f) {
  union { float f; unsigned int u; } a; a.f = f;
  unsigned int r = a.u + 0x7fffu + ((a.u >> 16) & 1u);   // RNE, inputs finite
  return (unsigned short)(r >> 16);
}

// silu + 6 cubic B-spline bases on the uniform extended grid
// knots g_j = -1 + (j-3)*(2/3), j=0..9.  u = (x+3)*1.5 puts knots at u=0..9.
// degree-1 bases are hats: b1_j = max(0, 1-|u-(j+1)|)  (matches Cox-de Boor
// recursion from the half-open degree-0 indicators, incl. x outside [-3,3]).
__device__ __forceinline__ s16x8 kan_act8(float x) {
  float sig = __builtin_amdgcn_rcpf(1.0f + __expf(-x));
  float s = x * sig;
  float u = fmaf(x, 1.5f, 4.5f);
  float b1[8];
#pragma unroll
  for (int j = 0; j < 8; ++j)
    b1[j] = fmaxf(0.0f, 1.0f - fabsf(u - (float)(j + 1)));
  float b2[7];
#pragma unroll
  for (int j = 0; j < 7; ++j) {
    float l = (u - (float)j) * 0.5f;
    float r = ((float)(j + 3) - u) * 0.5f;
    b2[j] = l * b1[j] + r * b1[j + 1];
  }
  float b3[6];
#pragma unroll
  for (int j = 0; j < 6; ++j) {
    float l = (u - (float)j) * (1.0f / 3.0f);
    float r = ((float)(j + 4) - u) * (1.0f / 3.0f);
    b3[j] = l * b2[j] + r * b2[j + 1];
  }
  s16x8 v;
  v[0] = (short)f2bf(s);
  v[1] = (short)f2bf(b3[0]);
  v[2] = (short)f2bf(b3[1]);
  v[3] = (short)f2bf(b3[2]);
  v[4] = (short)f2bf(b3[3]);
  v[5] = (short)f2bf(b3[4]);
  v[6] = (short)f2bf(b3[5]);
  v[7] = 0;
  return v;
}

// Pack weights: Wp[n][i*8+t] bf16; t=0 base_w, t=1..6 spline_w*scaler, t=7 zero.
// Rows n >= Nvalid (layer-2 pad to 256) are all-zero.
__global__ __launch_bounds__(256) void prep_w(
    const float* __restrict__ base_w, const float* __restrict__ spline_w,
    const float* __restrict__ scaler, short* __restrict__ Wp,
    int F, int Nvalid) {
  int i = blockIdx.x * 256 + threadIdx.x;   // feature
  int n = blockIdx.y;                       // output row
  if (i >= F) return;
  s16x8 v;
#pragma unroll
  for (int k = 0; k < 8; ++k) v[k] = 0;
  if (n < Nvalid) {
    int idx = n * F + i;
    float sc = scaler[idx];
    v[0] = (short)f2bf(base_w[idx]);
#pragma unroll
    for (int k = 0; k < 6; ++k) v[1 + k] = (short)f2bf(spline_w[idx * 6 + k] * sc);
  }
  *(s16x8*)&Wp[((size_t)n * F + i) * 8] = v;
}

// Fused activation GEMM: C[m][n] = sum_kk act(X)[m][kk] * W[n][kk]
// BM=BN=128, BK=64 (=8 features), 256 threads = 4 waves, 4x4 MFMA tiles/wave.
// LDS chunks (16B) XOR-swizzled: chunk c of row r lives at slot c^(r&7)
// -> <=2-way bank conflicts on both b128 writes and fragment reads.
__global__ __launch_bounds__(256, 2) void kan_gemm(
    const float* __restrict__ X, const short* __restrict__ W,
    float* __restrict__ C, int F, int ldc, int ncols) {
  __shared__ short As[128 * 64];
  __shared__ short Bs[128 * 64];

  const int t  = threadIdx.x;
  const int m0 = blockIdx.x * 128;
  const int n0 = blockIdx.y * 128;
  const int K  = F * 8;

  const int lane = t & 63;
  const int w    = t >> 6;
  const int wm   = (w >> 1) * 64;   // wave row offset in tile
  const int wn   = (w & 1) * 64;    // wave col offset in tile
  const int mrow = lane & 15;
  const int q    = lane >> 4;

  // loop-invariant LDS fragment offsets (shorts), ck=0; ck=1 is ^32
  int a_off[4], b_off[4];
#pragma unroll
  for (int it = 0; it < 4; ++it) {
    int r = wm + it * 16 + mrow;
    a_off[it] = r * 64 + ((q ^ (r & 7)) * 8);
    int n = wn + it * 16 + mrow;
    b_off[it] = n * 64 + ((q ^ (n & 7)) * 8);
  }

  // staging assignment: pair p = t + 256*j -> row = (p>>3), chunk = p&7
  const int srow = t >> 3;   // 0..31, +32 per j
  const int sc   = t & 7;
  const int sw_off = srow * 64 + ((sc ^ (srow & 7)) * 8);  // (srow+32j)&7 == srow&7
  const float* xp = X + (size_t)(m0 + srow) * F + sc;
  const short* wp = W + (size_t)(n0 + srow) * K + sc * 8;

  f32x4 acc[4][4] = {};

  const int ksteps = F >> 3;
  for (int ks = 0; ks < ksteps; ++ks) {
    // global loads up front
    float xv[4];
    s16x8 wv[4];
#pragma unroll
    for (int j = 0; j < 4; ++j)
      xv[j] = xp[(size_t)j * 32 * F + (size_t)ks * 8];
#pragma unroll
    for (int j = 0; j < 4; ++j)
      wv[j] = *(const s16x8*)&wp[(size_t)j * 32 * K + (size_t)ks * 64];
    // compute activations, stage A
#pragma unroll
    for (int j = 0; j < 4; ++j) {
      s16x8 av = kan_act8(xv[j]);
      *(s16x8*)&As[sw_off + j * 32 * 64] = av;
    }
    // stage B
#pragma unroll
    for (int j = 0; j < 4; ++j)
      *(s16x8*)&Bs[sw_off + j * 32 * 64] = wv[j];
    __syncthreads();

#pragma unroll
    for (int ck = 0; ck < 2; ++ck) {
      s16x8 af[4], bfr[4];
#pragma unroll
      for (int it = 0; it < 4; ++it)
        af[it] = *(const s16x8*)&As[a_off[it] ^ (ck * 32)];
#pragma unroll
      for (int it = 0; it < 4; ++it)
        bfr[it] = *(const s16x8*)&Bs[b_off[it] ^ (ck * 32)];
#pragma unroll
      for (int a = 0; a < 4; ++a)
#pragma unroll
        for (int b = 0; b < 4; ++b)
          acc[a][b] = __builtin_amdgcn_mfma_f32_16x16x32_bf16(
              af[a], bfr[b], acc[a][b], 0, 0, 0);
    }
    __syncthreads();
  }

  // epilogue: C/D layout col=lane&15, row=quad*4+reg (m89/m91 verified)
#pragma unroll
  for (int a = 0; a < 4; ++a) {
#pragma unroll
    for (int b = 0; b < 4; ++b) {
      int col = n0 + wn + b * 16 + mrow;
      if (col < ncols) {
#pragma unroll
        for (int r = 0; r < 4; ++r) {
          int row = m0 + wm + a * 16 + q * 4 + r;
          C[(size_t)row * ldc + col] = acc[a][b][r];
        }
      }
    }
  }
}

// In-place LayerNorm over D=512, one wave per row.
__global__ __launch_bounds__(256) void ln_kern(
    float* __restrict__ h, const float* __restrict__ gamma,
    const float* __restrict__ beta) {
  int lane = threadIdx.x & 63;
  int wv   = threadIdx.x >> 6;
  int row  = blockIdx.x * 4 + wv;
  float* hp = h + (size_t)row * 512 + lane * 8;
  f32x4 v0 = *(f32x4*)hp;
  f32x4 v1 = *(f32x4*)(hp + 4);
  float s = 0.f, s2 = 0.f;
#pragma unroll
  for (int k = 0; k < 4; ++k) { s += v0[k] + v1[k]; s2 += v0[k]*v0[k] + v1[k]*v1[k]; }
#pragma unroll
  for (int m = 32; m >= 1; m >>= 1) {
    s  += __shfl_xor(s,  m, 64);
    s2 += __shfl_xor(s2, m, 64);
  }
  float mean = s * (1.0f / 512.0f);
  float var  = s2 * (1.0f / 512.0f) - mean * mean;
  float rstd = rsqrtf(var + 1e-5f);
  const f32x4 g0 = *(const f32x4*)(gamma + lane * 8);
  const f32x4 g1 = *(const f32x4*)(gamma + lane * 8 + 4);
  const f32x4 be0 = *(const f32x4*)(beta + lane * 8);
  const f32x4 be1 = *(const f32x4*)(beta + lane * 8 + 4);
#pragma unroll
  for (int k = 0; k < 4; ++k) {
    v0[k] = (v0[k] - mean) * rstd * g0[k] + be0[k];
    v1[k] = (v1[k] - mean) * rstd * g1[k] + be1[k];
  }
  *(f32x4*)hp = v0;
  *(f32x4*)(hp + 4) = v1;
}

extern "C" void kernel_launch(void* const* d_in, const int* in_sizes, int n_in,
                              void* d_out, int out_size, void* d_ws, size_t ws_size,
                              hipStream_t stream) {
  const float* x         = (const float*)d_in[0];
  const float* base_w1   = (const float*)d_in[1];
  const float* spline_w1 = (const float*)d_in[2];
  const float* scaler1   = (const float*)d_in[3];
  const float* ln_gamma  = (const float*)d_in[4];
  const float* ln_beta   = (const float*)d_in[5];
  const float* base_w2   = (const float*)d_in[6];
  const float* spline_w2 = (const float*)d_in[7];
  const float* scaler2   = (const float*)d_in[8];
  float* out = (float*)d_out;

  const int B = 16384, D_IN = 1280, D_HID = 512, D_OUT = 229;
  const int N2P = 256;  // layer-2 W rows padded to 256

  // ws layout (all 16B aligned): W1p | W2p | h   (~46.1 MB total)
  char* ws = (char*)d_ws;
  short* W1p = (short*)ws;                                   // 512*1280*8 bf16
  short* W2p = (short*)(ws + (size_t)D_HID * D_IN * 8 * 2);  // 256*512*8 bf16
  float* h   = (float*)(ws + (size_t)D_HID * D_IN * 8 * 2
                           + (size_t)N2P * D_HID * 8 * 2);   // 16384*512 f32

  prep_w<<<dim3(D_IN / 256, D_HID), 256, 0, stream>>>(
      base_w1, spline_w1, scaler1, W1p, D_IN, D_HID);
  prep_w<<<dim3(D_HID / 256, N2P), 256, 0, stream>>>(
      base_w2, spline_w2, scaler2, W2p, D_HID, D_OUT);

  kan_gemm<<<dim3(B / 128, D_HID / 128), 256, 0, stream>>>(
      x, W1p, h, D_IN, D_HID, D_HID);

  ln_kern<<<dim3(B / 4), 256, 0, stream>>>(h, ln_gamma, ln_beta);

  kan_gemm<<<dim3(B / 128, 2), 256, 0, stream>>>(
      h, W2p, out, D_HID, D_OUT, D_OUT);
}